// Round 20
// baseline (74.915 us; speedup 1.0000x reference)
//
#include <hip/hip_runtime.h>
#include <hip/hip_bf16.h>

#define ALPHA 0.2f
#define NROW 8192

typedef __attribute__((ext_vector_type(4))) float f4;
typedef __attribute__((ext_vector_type(8))) short s8;

__device__ __forceinline__ short f2bf_bits(float x){
    __hip_bfloat16 b = __float2bfloat16(x);
    return __builtin_bit_cast(short, b);
}

__device__ __forceinline__ void gload_lds16(const void* g, void* l){
    __builtin_amdgcn_global_load_lds(
        (const __attribute__((address_space(1))) void*)g,
        (__attribute__((address_space(3))) void*)l, 16, 0, 0);
}

// K1: h = x@W ; s1 ; F1=exp(s2) ; F2=exp(0.2*s2) ; hpack in MFMA B-fragment order.
__global__ __launch_bounds__(256) void k_proj(
    const float* __restrict__ x, const float* __restrict__ W, const float* __restrict__ a,
    float* __restrict__ s1,
    float* __restrict__ F1, float* __restrict__ F2, __hip_bfloat16* __restrict__ hpack)
{
    __shared__ float Wsh[128*64];   // 32 KB
    __shared__ float xsh[32*128];   // 16 KB
    const int t = threadIdx.x;
    const int f = t & 63, wq = t >> 6;
    const int row0 = blockIdx.x * 32;
    for (int i = t; i < 128*64; i += 256) Wsh[i] = W[i];
    for (int i = t; i < 32*128; i += 256) xsh[i] = x[row0*128 + i];
    __syncthreads();
    const float a1 = a[f], a2 = a[64 + f];
    #pragma unroll 1
    for (int rr = 0; rr < 8; ++rr){
        const int ry = wq*8 + rr;
        float acc = 0.f;
        #pragma unroll
        for (int k = 0; k < 128; ++k) acc = fmaf(xsh[ry*128 + k], Wsh[k*64 + f], acc);
        float p1 = acc * a1, p2 = acc * a2;
        #pragma unroll
        for (int m = 32; m; m >>= 1){ p1 += __shfl_xor(p1, m, 64); p2 += __shfl_xor(p2, m, 64); }
        const int j = row0 + ry;
        if (f == 0){
            s1[j] = p1;
            F1[j] = __expf(p2); F2[j] = __expf(0.2f * p2);
        }
        const int sc = j >> 5, hg = (j >> 3) & 3, e = j & 7;
        const int fg = f >> 4, lr = f & 15;
        hpack[(((sc*4 + fg)*64) + hg*16 + lr)*8 + e] = __float2bfloat16(acc);
    }
}

// K3: R19 structure + rule-#18 fix: sched_barrier(0) after EVERY s_waitcnt so
// register-only consumers (ballots) of asm-pinned loads cannot hoist above the
// wait. 2 blocks/CU (73728 B LDS); 4 asm-pinned reg slots; 4 windows of 8
// steps; h dbuf 2x32KB retired by step-4's W6 before the raw barrier.
__global__ __launch_bounds__(512, 4) void k_gat(
    const float* __restrict__ adj, const float* __restrict__ s1g,
    const float* __restrict__ F1g, const float* __restrict__ F2g,
    const __hip_bfloat16* __restrict__ hpack,
    float* __restrict__ part, float* __restrict__ pden)
{
    __shared__ __attribute__((aligned(16))) char arena[73728]; // 2x32K h + 4K F1 + 4K F2

    const int tid = threadIdx.x;
    const int w = tid >> 6, lane = tid & 63;
    const int lr = lane & 15, hi = lane >> 4;
    const int jslab = blockIdx.x >> 6, igrp = blockIdx.x & 63;

    float* F1sl = (float*)(arena + 65536);
    float* F2sl = (float*)(arena + 69632);

    const int rbA = igrp*128 + w*16;
    const int row = rbA + lr;
    const float s1r = s1g[row];
    const float E1 = __expf(s1r), E2 = __expf(ALPHA*s1r), T1 = __expf(-s1r);
    const int hi8 = hi * 8;

#define STAGEH(buf, sw_) do { \
    const s8* hp_ = (const s8*)hpack + (jslab*32 + (sw_)*8)*256 + w*256 + lane; \
    char* dst_ = arena + (buf)*32768 + w*4096; \
    _Pragma("unroll") \
    for (int it_ = 0; it_ < 4; ++it_) \
        gload_lds16(hp_ + it_*64, dst_ + it_*1024); \
} while(0)

    // adj per-lane pointer: rows rbA + (lane>>3) (+8 for 2nd load), cols (lane&7)*4
    const float* padj = adj + (long)(rbA + (lane >> 3))*NROW + jslab*1024 + (lane & 7)*4;
    const unsigned bsh = (unsigned)((lr & 7)*8 + hi*2);

    f4 acc0={0,0,0,0}, acc1={0,0,0,0}, acc2={0,0,0,0}, acc3={0,0,0,0};
    float lsum = 0.f;

    f4 v0S0,v1S0, v0S1,v1S1, v0S2,v1S2, v0S3,v1S3;

// asm-pinned loads: values cannot be sunk or rematerialized by the compiler
#define LOADA(S, s_) do { \
    const float* p0_ = padj + (s_) * 32; \
    const float* p1_ = p0_ + 8*NROW; \
    asm volatile("global_load_dwordx4 %0, %2, off\n\t" \
                 "global_load_dwordx4 %1, %3, off" \
        : "=&v"(v0##S), "=&v"(v1##S) : "v"(p0_), "v"(p1_) : "memory"); \
} while(0)

#define CALCQ(cond, g1, g2, qd) { \
    float fz = ((g1) > T1) ? (g1) * E1 : (g2) * E2; \
    qd = (cond) ? fz : 0.f; }

#define STEP(S, s_) do { \
    unsigned long long c0_ = __ballot(v0##S[0] > 0.f); \
    unsigned long long c1_ = __ballot(v0##S[1] > 0.f); \
    unsigned long long c2_ = __ballot(v0##S[2] > 0.f); \
    unsigned long long c3_ = __ballot(v0##S[3] > 0.f); \
    unsigned long long d0_ = __ballot(v1##S[0] > 0.f); \
    unsigned long long d1_ = __ballot(v1##S[1] > 0.f); \
    unsigned long long d2_ = __ballot(v1##S[2] > 0.f); \
    unsigned long long d3_ = __ballot(v1##S[3] > 0.f); \
    const unsigned u0 = (unsigned)(((lr < 8) ? c0_ : d0_) >> bsh); \
    const unsigned u1 = (unsigned)(((lr < 8) ? c1_ : d1_) >> bsh); \
    const unsigned u2 = (unsigned)(((lr < 8) ? c2_ : d2_) >> bsh); \
    const unsigned u3 = (unsigned)(((lr < 8) ? c3_ : d3_) >> bsh); \
    const s8* hb_ = (const s8*)(arena + (((s_) >> 3) & 1)*32768) + ((s_) & 7)*256; \
    s8 h0 = hb_[lane]; s8 h1 = hb_[64 + lane]; \
    s8 h2 = hb_[128 + lane]; s8 h3 = hb_[192 + lane]; \
    f4 f1a = *(const f4*)&F1sl[(s_)*32 + hi8]; f4 f1b = *(const f4*)&F1sl[(s_)*32 + hi8 + 4]; \
    f4 f2a = *(const f4*)&F2sl[(s_)*32 + hi8]; f4 f2b = *(const f4*)&F2sl[(s_)*32 + hi8 + 4]; \
    float q0,q1,q2,q3,q4,q5,q6,q7; \
    CALCQ(u0 & 1u, f1a[0], f2a[0], q0); CALCQ(u1 & 1u, f1a[1], f2a[1], q1); \
    CALCQ(u2 & 1u, f1a[2], f2a[2], q2); CALCQ(u3 & 1u, f1a[3], f2a[3], q3); \
    CALCQ(u0 & 2u, f1b[0], f2b[0], q4); CALCQ(u1 & 2u, f1b[1], f2b[1], q5); \
    CALCQ(u2 & 2u, f1b[2], f2b[2], q6); CALCQ(u3 & 2u, f1b[3], f2b[3], q7); \
    lsum += ((q0+q1)+(q2+q3)) + ((q4+q5)+(q6+q7)); \
    s8 af; \
    af[0]=f2bf_bits(q0); af[1]=f2bf_bits(q1); af[2]=f2bf_bits(q2); af[3]=f2bf_bits(q3); \
    af[4]=f2bf_bits(q4); af[5]=f2bf_bits(q5); af[6]=f2bf_bits(q6); af[7]=f2bf_bits(q7); \
    acc0 = __builtin_amdgcn_mfma_f32_16x16x32_bf16(af, h0, acc0, 0, 0, 0); \
    acc1 = __builtin_amdgcn_mfma_f32_16x16x32_bf16(af, h1, acc1, 0, 0, 0); \
    acc2 = __builtin_amdgcn_mfma_f32_16x16x32_bf16(af, h2, acc2, 0, 0, 0); \
    acc3 = __builtin_amdgcn_mfma_f32_16x16x32_bf16(af, h3, acc3, 0, 0, 0); \
} while(0)

// rule #18: sched_barrier(0) right after each waitcnt so no register-only
// consumer of the asm-load results can be hoisted above the wait.
#define W10 do { asm volatile("s_waitcnt vmcnt(10)" ::: "memory"); \
                 __builtin_amdgcn_sched_barrier(0); } while(0)
#define W6  do { asm volatile("s_waitcnt vmcnt(6)"  ::: "memory"); \
                 __builtin_amdgcn_sched_barrier(0); } while(0)
#define WN(n) do { asm volatile("s_waitcnt vmcnt(" #n ")" ::: "memory"); \
                 __builtin_amdgcn_sched_barrier(0); } while(0)

    // prologue: h window 0 -> buf0 (4 vm), F slab, slots 0..3 (8 vm); drain once
    STAGEH(0, 0);
    *(float2*)&F1sl[tid*2] = *(const float2*)(F1g + jslab*1024 + tid*2);
    *(float2*)&F2sl[tid*2] = *(const float2*)(F2g + jslab*1024 + tid*2);
    LOADA(S0, 0); LOADA(S1, 1); LOADA(S2, 2); LOADA(S3, 3);
    __syncthreads();

    // windows 0..2: stage next h (4 ops), 8 steps (W10 x4 then W6 x4), raw barrier.
    // step-4's W6 retires the stage ops -> h visible to all waves before barrier.
    #pragma unroll 1
    for (int sw = 0; sw < 3; ++sw){
        const int st = sw * 8;
        STAGEH((sw + 1) & 1, sw + 1);
        W10; STEP(S0, st    ); LOADA(S0, st + 4);
        W10; STEP(S1, st + 1); LOADA(S1, st + 5);
        W10; STEP(S2, st + 2); LOADA(S2, st + 6);
        W10; STEP(S3, st + 3); LOADA(S3, st + 7);
        W6;  STEP(S0, st + 4); LOADA(S0, st + 8);
        W6;  STEP(S1, st + 5); LOADA(S1, st + 9);
        W6;  STEP(S2, st + 6); LOADA(S2, st + 10);
        W6;  STEP(S3, st + 7); LOADA(S3, st + 11);
        asm volatile("s_barrier" ::: "memory");   // raw: no vmcnt drain
    }
    // window 3 (steps 24..31): no staging; drain ladder
    W6; STEP(S0, 24); LOADA(S0, 28);
    W6; STEP(S1, 25); LOADA(S1, 29);
    W6; STEP(S2, 26); LOADA(S2, 30);
    W6; STEP(S3, 27); LOADA(S3, 31);
    W6;    STEP(S0, 28);
    WN(4); STEP(S1, 29);
    WN(2); STEP(S2, 30);
    WN(0); STEP(S3, 31);

#undef STAGEH
#undef LOADA
#undef CALCQ
#undef STEP
#undef W10
#undef W6
#undef WN

    lsum += __shfl_xor(lsum, 16, 64);
    lsum += __shfl_xor(lsum, 32, 64);

    // partial stores (C layout: col = lr, row = hi*4 + r, col-block q*16)
    {
        const long pb = ((long)jslab*NROW + rbA + hi*4)*64 + lr;
        #pragma unroll
        for (int r = 0; r < 4; ++r){
            part[pb + r*64 +  0] = acc0[r];
            part[pb + r*64 + 16] = acc1[r];
            part[pb + r*64 + 32] = acc2[r];
            part[pb + r*64 + 48] = acc3[r];
        }
        if (lane < 16) pden[jslab*NROW + rbA + lr] = lsum;
    }
}

// K4: combine 8 jslab partials, divide, ELU, store out.
__global__ __launch_bounds__(256) void k_comb(
    const float* __restrict__ part, const float* __restrict__ pden,
    float* __restrict__ out)
{
    const int idx = blockIdx.x*256 + threadIdx.x;   // 8192*16
    const int i = idx >> 4, c4 = (idx & 15) << 2;
    f4 sa = {0.f,0.f,0.f,0.f}; float L = 0.f;
    #pragma unroll
    for (int s = 0; s < 8; ++s){
        sa += *(const f4*)&part[((long)s*NROW + i)*64 + c4];
        L  += pden[s*NROW + i];
    }
    const float inv = 1.f / L;
    f4 o;
    #pragma unroll
    for (int e = 0; e < 4; ++e){
        float v = sa[e] * inv;
        o[e] = (v > 0.f) ? v : expm1f(v);
    }
    *(f4*)&out[(long)i*64 + c4] = o;
}

extern "C" void kernel_launch(void* const* d_in, const int* in_sizes, int n_in,
                              void* d_out, int out_size, void* d_ws, size_t ws_size,
                              hipStream_t stream)
{
    const float* x   = (const float*)d_in[0];
    const float* adj = (const float*)d_in[1];
    const float* W   = (const float*)d_in[2];
    const float* a   = (const float*)d_in[3];
    float* out = (float*)d_out;

    char* ws = (char*)d_ws;
    float* s1   = (float*)(ws);                    // 32 KB
    float* F1   = (float*)(ws + 65536);            // 32 KB
    float* F2   = (float*)(ws + 98304);            // 32 KB
    __hip_bfloat16* hpack = (__hip_bfloat16*)(ws + 131328);   // 1 MB
    float* part = (float*)(ws + 1179904);          // 16 MB (8 x 8192 x 64)
    float* pden = (float*)(ws + 17957120);         // 256 KB (8 x 8192)

    k_proj <<<256, 256, 0, stream>>>(x, W, a, s1, F1, F2, hpack);
    k_gat  <<<512, 512, 0, stream>>>(adj, s1, F1, F2, hpack, part, pden);
    k_comb <<<512, 256, 0, stream>>>(part, pden, out);
}